// Round 14
// baseline (3144.058 us; speedup 1.0000x reference)
//
#include <hip/hip_runtime.h>

#define NB 32
#define NT 1024
#define NH 512
#define NE 256
#define NV0 2048
#define NV1 512
#define G3H 1536
#define NCHUNK 16       // hh chunks (32 hh x 3 gates each)
#define FPB 16416       // flag ints per batch: 1026 levels x 16 chunks

typedef __attribute__((ext_vector_type(8))) short bf16x8;
typedef __attribute__((ext_vector_type(4))) float f32x4;
typedef unsigned short u16;
typedef unsigned int u32;
typedef unsigned long long u64;

__device__ __forceinline__ u16 bf16_hi(float x) {
  unsigned u = __float_as_uint(x);
  unsigned r = (u + 0x7FFF + ((u >> 16) & 1)) >> 16;
  return (u16)r;
}
__device__ __forceinline__ float bf16_f(u16 h) {
  return __uint_as_float(((unsigned)h) << 16);
}
__device__ __forceinline__ u32 pack_hl(float v) {
  u16 hi = bf16_hi(v);
  u16 lo = bf16_hi(v - bf16_f(hi));
  return (u32)hi | ((u32)lo << 16);
}
__device__ __forceinline__ float unpack_hl(u32 w) {
  return bf16_f((u16)w) + bf16_f((u16)(w >> 16));
}

// ---------------- prep ----------------

__global__ void k_transpose(const float* __restrict__ in, float* __restrict__ out) {
  __shared__ float tile[32][33];
  int bx = blockIdx.x, by = blockIdx.y;
  int x = threadIdx.x, y = threadIdx.y;
  #pragma unroll
  for (int j = 0; j < 4; ++j)
    tile[y + j * 8][x] = in[(by * 32 + y + j * 8) * 512 + bx * 32 + x];
  __syncthreads();
  #pragma unroll
  for (int j = 0; j < 4; ++j)
    out[(bx * 32 + y + j * 8) * 1536 + by * 32 + x] = tile[x][y + j * 8];
}

__global__ __launch_bounds__(256) void k_proj(const float* __restrict__ emb0,
                                              const float* __restrict__ emb1,
                                              const float* __restrict__ Wt_ih,
                                              float* __restrict__ proj0,
                                              float* __restrict__ proj1) {
  __shared__ float a[8][NE];
  int g0 = blockIdx.x * 8;
  int tid = threadIdx.x;
  for (int i = tid; i < 8 * NE; i += 256) {
    int v = g0 + (i >> 8);
    int k = i & 255;
    a[i >> 8][k] = (v < NV0) ? emb0[v * NE + k] : emb1[(v - NV0) * NE + k];
  }
  __syncthreads();
  bool is0 = (g0 < NV0);
  int koff = is0 ? 0 : NE;
  float acc[8][6];
  #pragma unroll
  for (int v = 0; v < 8; ++v)
    #pragma unroll
    for (int j = 0; j < 6; ++j) acc[v][j] = 0.f;
  for (int k = 0; k < NE; ++k) {
    const float* wrow = Wt_ih + (size_t)(k + koff) * G3H;
    float w[6];
    #pragma unroll
    for (int j = 0; j < 6; ++j) w[j] = wrow[tid + j * 256];
    #pragma unroll
    for (int v = 0; v < 8; ++v) {
      float av = a[v][k];
      #pragma unroll
      for (int j = 0; j < 6; ++j) acc[v][j] += av * w[j];
    }
  }
  float* outp = is0 ? (proj0 + (size_t)g0 * G3H) : (proj1 + (size_t)(g0 - NV0) * G3H);
  for (int v = 0; v < 8; ++v)
    for (int j = 0; j < 6; ++j)
      outp[(size_t)v * G3H + tid + j * 256] = acc[v][j];
}

// W_hh split: tile tt = (hh>>4)*3 + g  (32 hh16-blocks x 3 gates = 96 tiles of 16x512)
__global__ void k_wsplit(const float* __restrict__ W_hh, u16* __restrict__ Wfh,
                         u16* __restrict__ Wfl) {
  int idx = blockIdx.x * blockDim.x + threadIdx.x;
  if (idx >= G3H * NH) return;
  int row = idx >> 9, k = idx & 511;
  int g = row >> 9, hh = row & 511;
  int tt = (hh >> 4) * 3 + g;
  size_t phys = ((size_t)tt * 64 + (k >> 3)) * 128 + (hh & 15) * 8 + (k & 7);
  float v = W_hh[idx];
  u16 hi = bf16_hi(v);
  Wfh[phys] = hi;
  Wfl[phys] = bf16_hi(v - bf16_f(hi));
}

__global__ void k_wsplit_dec(const float* __restrict__ W, u16* __restrict__ Wh,
                             u16* __restrict__ Wl, int R) {
  int idx = blockIdx.x * blockDim.x + threadIdx.x;
  if (idx >= R * 512) return;
  int row = idx >> 9, k = idx & 511;
  size_t phys = ((size_t)(row >> 4) * 64 + (k >> 3)) * 128 + (row & 15) * 8 + (k & 7);
  float v = W[idx];
  u16 hi = bf16_hi(v);
  Wh[phys] = hi;
  Wl[phys] = bf16_hi(v - bf16_f(hi));
}

// Fused planning: one block per batch. Computes levels, builds level-ordered
// item list (groups of <=16) + node_list, inits state row 0 and per-chunk flags.
__global__ __launch_bounds__(256) void k_plan(const int* __restrict__ cond,
                                              const float* __restrict__ hidden,
                                              u32* __restrict__ bufp,
                                              int* __restrict__ gflag,
                                              int* __restrict__ items,
                                              int* __restrict__ nitems,
                                              int* __restrict__ node_list) {
  __shared__ int c_lds[NT];
  __shared__ int lvl[NT + 1];
  __shared__ int off[NT + 1];
  int b = blockIdx.x, tid = threadIdx.x;
  for (int h = tid; h < NH; h += 256) bufp[b * NH + h] = pack_hl(hidden[b * NH + h]);
  for (int f = tid; f < FPB; f += 256) gflag[b * FPB + f] = (f < 16) ? 1 : 0;
  for (int i = tid; i < NT; i += 256) c_lds[i] = cond[b * NT + i];
  for (int i = tid; i <= NT; i += 256) off[i] = 0;
  __syncthreads();
  if (tid == 0) {
    lvl[0] = 0;
    for (int t = 0; t < NT; ++t) {
      int l = lvl[c_lds[t]] + 1;
      lvl[t + 1] = l;
      off[l - 1]++;                       // counts
    }
    int off0 = 0, io = 0;
    for (int p = 0; p <= NT; ++p) {
      int n = off[p];
      off[p] = off0;                      // counts -> offsets
      for (int g0 = 0; g0 < n; g0 += 16) {
        int nb = n - g0; if (nb > 16) nb = 16;
        items[b * 1024 + io++] = (p << 21) | ((b * 1024 + off0 + g0) << 6) | nb;
      }
      off0 += n;
    }
    nitems[b] = io;
    for (int t = 0; t < NT; ++t) {        // scatter (offsets become cursors)
      int p = lvl[t + 1] - 1;
      node_list[b * 1024 + off[p]++] = (b << 16) | t;
    }
  }
}

// ---------------- recurrence: per-batch level streams, slim protocol ----------------
// Grid = 16 chunks x 32 batches = 512 blocks of 128 threads (2 waves), 2 blocks/CU.
// Per (batch,level,chunk) FLAG ARRAY (16 ints = one 64B line): producer publishes
// with ONE release atomic STORE (no RMW serialization); consumer thread tid&15
// polls its chunk's flag -- the wave's exec-mask loop exits only when all 16
// lanes see set, preserving the all-chunks-ready guarantee.
// Metadata double-buffered (s_*[2][16]): next item's node_list->cond/tok chain
// issues post-poll and lands in the alternate slot before the publish barrier.
// 2 barriers/item (post-stage, pre-publish) vs r13's 4.
// Race discipline (r7/r10-proven): per-thread vmcnt(0) drain + barrier before
// the single release store; consumer relaxed-poll + compiler barrier; all state
// traffic is L3-coherent agent atomics.

__global__ __launch_bounds__(128, 8) void rnn_steps(
    const int* __restrict__ items, const int* __restrict__ nitems,
    const int* __restrict__ node_list, const int* __restrict__ cond,
    const int* __restrict__ tok0, const int* __restrict__ tok1,
    const u16* __restrict__ Wfh, const u16* __restrict__ Wfl,
    const float* __restrict__ proj0, const float* __restrict__ proj1,
    const float* __restrict__ b_ih, const float* __restrict__ b_hh,
    u32* __restrict__ bufp, int* gflag) {
  __shared__ unsigned char hds_h[16 * 1024];
  __shared__ unsigned char hds_l[16 * 1024];
  __shared__ int s_tb[2][16], s_par[2][16], s_k0[2][16], s_k1[2][16];
  int tid = threadIdx.x;
  int w = tid >> 6, lane = tid & 63, q = lane >> 4, m = lane & 15;
  int c = blockIdx.x & (NCHUNK - 1);
  int b = blockIdx.x >> 4;
  int nIt = nitems[b];
  const int* myItems = items + b * 1024;
  int* myF = gflag + b * FPB;
  // wave-invariant constants
  int hb = c * 2 + w;          // hh16-block owned by this wave
  int hh = hb * 16 + m;
  float bir = b_ih[hh] + b_hh[hh];
  float biz = b_ih[NH + hh] + b_hh[NH + hh];
  float bin = b_ih[2 * NH + hh];
  float bhn = b_hh[2 * NH + hh];
  const u16* wh = Wfh + (size_t)hb * 3 * 8192;
  const u16* wl = Wfl + (size_t)hb * 3 * 8192;
  // fill metadata slot 0
  {
    int d0 = myItems[0];
    int st0 = (d0 >> 6) & 0x7FFF, nb0 = d0 & 63;
    if (tid < 16) {
      int bb = 0, t = -1, par = 0, q0 = 0, q1 = 0;
      if (tid < nb0) {
        int pk = node_list[st0 + tid];
        bb = pk >> 16; t = pk & 0xFFFF;
        par = cond[bb * NT + t];
        q0 = tok0[bb * NT + t];
        q1 = tok1[bb * NT + t];
      }
      s_tb[0][tid] = (t + 1) * NB + bb;
      s_par[0][tid] = par * NB + bb;
      s_k0[0][tid] = q0; s_k1[0][tid] = q1;
    }
    __syncthreads();
  }
  int prevp = -1;
  for (int j = 0; j < nIt; ++j) {
    int cur = j & 1;
    int desc = myItems[j];
    int p = desc >> 21;
    int nb = desc & 63;
    // ---- gi gather (independent of parents): seeds accumulators, pre-poll ----
    f32x4 aR, aZ, aN;
    float gin[4];
    #pragma unroll
    for (int i = 0; i < 4; ++i) {
      int node = q * 4 + i;
      const float* p0 = proj0 + (size_t)s_k0[cur][node] * G3H;
      const float* p1 = proj1 + (size_t)s_k1[cur][node] * G3H;
      aR[i] = p0[hh] + p1[hh] + bir;
      aZ[i] = p0[NH + hh] + p1[NH + hh] + biz;
      gin[i] = p0[2 * NH + hh] + p1[2 * NH + hh] + bin;
      aN[i] = bhn;
    }
    // ---- poll: 16 per-chunk flags (one 64B line), exec-mask loop = all set ----
    if (p != prevp) {
      const int* f = myF + p * 16 + (tid & 15);
      while (__hip_atomic_load(f, __ATOMIC_RELAXED, __HIP_MEMORY_SCOPE_AGENT) == 0)
        __builtin_amdgcn_s_sleep(1);
      prevp = p;
    }
    asm volatile("" ::: "memory");
    // ---- prefetch next item's metadata (chain hides under stage) ----
    int hasNext = (j + 1 < nIt);
    int nextdesc = hasNext ? myItems[j + 1] : 0;
    int n_tb = 0, n_par = 0, n_k0 = 0, n_k1 = 0;
    if (hasNext && tid < 16) {
      int st2 = (nextdesc >> 6) & 0x7FFF, nb2 = nextdesc & 63;
      int bb = 0, t = -1, par = 0, q0 = 0, q1 = 0;
      if (tid < nb2) {
        int pk = node_list[st2 + tid];
        bb = pk >> 16; t = pk & 0xFFFF;
        par = cond[bb * NT + t];
        q0 = tok0[bb * NT + t];
        q1 = tok1[bb * NT + t];
      }
      n_tb = (t + 1) * NB + bb;
      n_par = par * NB + bb;
      n_k0 = q0; n_k1 = q1;
    }
    // ---- stage nb parent states into split hi/lo LDS (swizzled) ----
    for (int idx = tid; idx < nb * 16; idx += 128) {
      int r = idx >> 4, seg = idx & 15;
      size_t src = (size_t)s_par[cur][r] * NH + seg * 32;
      u64 dv[16];
      #pragma unroll
      for (int k2 = 0; k2 < 16; ++k2)
        dv[k2] = __hip_atomic_load((const u64*)&bufp[src + k2 * 2],
                                   __ATOMIC_RELAXED, __HIP_MEMORY_SCOPE_AGENT);
      int swz = (r & 7) << 4;
      #pragma unroll
      for (int k2 = 0; k2 < 16; ++k2) {
        u32 e0 = (u32)dv[k2], e1 = (u32)(dv[k2] >> 32);
        int wi = seg * 32 + k2 * 2;
        int a = r * 1024 + (((wi >> 3) * 16) ^ swz) + ((2 * wi) & 15);
        *(u32*)(hds_h + a) = (e0 & 0xFFFFu) | (e1 << 16);
        *(u32*)(hds_l + a) = (e0 >> 16) | (e1 & 0xFFFF0000u);
      }
    }
    __syncthreads();
    // ---- MFMA: wave owns hb = c*2+w, 3 gates, 16 nodes, K=512, 3-split ----
    #pragma unroll 4
    for (int s = 0; s < 16; ++s) {
      int ab = m * 1024 + (((s * 64) + (q * 16)) ^ ((m & 7) << 4));
      bf16x8 ah = *(const bf16x8*)(hds_h + ab);
      bf16x8 al = *(const bf16x8*)(hds_l + ab);
      int koff = (s * 4 + q) * 128 + m * 8;
      bf16x8 bh0 = *(const bf16x8*)(wh + koff);
      bf16x8 bl0 = *(const bf16x8*)(wl + koff);
      bf16x8 bh1 = *(const bf16x8*)(wh + 8192 + koff);
      bf16x8 bl1 = *(const bf16x8*)(wl + 8192 + koff);
      bf16x8 bh2 = *(const bf16x8*)(wh + 16384 + koff);
      bf16x8 bl2 = *(const bf16x8*)(wl + 16384 + koff);
      aR = __builtin_amdgcn_mfma_f32_16x16x32_bf16(ah, bh0, aR, 0, 0, 0);
      aR = __builtin_amdgcn_mfma_f32_16x16x32_bf16(ah, bl0, aR, 0, 0, 0);
      aR = __builtin_amdgcn_mfma_f32_16x16x32_bf16(al, bh0, aR, 0, 0, 0);
      aZ = __builtin_amdgcn_mfma_f32_16x16x32_bf16(ah, bh1, aZ, 0, 0, 0);
      aZ = __builtin_amdgcn_mfma_f32_16x16x32_bf16(ah, bl1, aZ, 0, 0, 0);
      aZ = __builtin_amdgcn_mfma_f32_16x16x32_bf16(al, bh1, aZ, 0, 0, 0);
      aN = __builtin_amdgcn_mfma_f32_16x16x32_bf16(ah, bh2, aN, 0, 0, 0);
      aN = __builtin_amdgcn_mfma_f32_16x16x32_bf16(ah, bl2, aN, 0, 0, 0);
      aN = __builtin_amdgcn_mfma_f32_16x16x32_bf16(al, bh2, aN, 0, 0, 0);
    }
    // ---- in-register GRU epilogue; packed u32 agent-atomic state stores ----
    #pragma unroll
    for (int i = 0; i < 4; ++i) {
      int node = q * 4 + i;
      if (node < nb) {
        float rg = 1.f / (1.f + __expf(-aR[i]));
        float zg = 1.f / (1.f + __expf(-aZ[i]));
        float nn = 1.f - 2.f / (1.f + __expf(2.f * (gin[i] + rg * aN[i])));
        int hofs = node * 1024 + ((hh * 2) ^ ((node & 7) << 4));
        float hp = bf16_f(*(const u16*)(hds_h + hofs)) + bf16_f(*(const u16*)(hds_l + hofs));
        float hn = (1.f - zg) * nn + zg * hp;
        __hip_atomic_store(&bufp[(size_t)s_tb[cur][node] * NH + hh], pack_hl(hn),
                           __ATOMIC_RELAXED, __HIP_MEMORY_SCOPE_AGENT);
      }
    }
    // ---- drain all threads' stores; swap metadata slot; barrier; publish ----
    bool lastOfLevel = (j == nIt - 1) || ((nextdesc >> 21) != p);
    asm volatile("s_waitcnt vmcnt(0)" ::: "memory");
    if (hasNext && tid < 16) {
      s_tb[cur ^ 1][tid] = n_tb;
      s_par[cur ^ 1][tid] = n_par;
      s_k0[cur ^ 1][tid] = n_k0;
      s_k1[cur ^ 1][tid] = n_k1;
    }
    __syncthreads();
    if (lastOfLevel && tid == 0)
      __hip_atomic_store(myF + (p + 1) * 16 + c, 1, __ATOMIC_RELEASE,
                         __HIP_MEMORY_SCOPE_AGENT);
  }
}

// ---------------- decode GEMM: MFMA bf16 3-split, 64x128 tiles ----------------

__global__ __launch_bounds__(256) void k_dec(const u32* __restrict__ bufp,
                                             const u16* __restrict__ Wh,
                                             const u16* __restrict__ Wl,
                                             const float* __restrict__ bias,
                                             float* __restrict__ out, int N) {
  __shared__ u16 Ah[64 * 128];
  __shared__ u16 Al[64 * 128];
  int tid = threadIdx.x;
  int w = tid >> 6, lane = tid & 63, q = lane >> 4, m = lane & 15;
  int n0 = blockIdx.x * 128, m0 = blockIdx.y * 64;
  f32x4 acc[8];
  #pragma unroll
  for (int n = 0; n < 8; ++n) acc[n] = (f32x4){0.f, 0.f, 0.f, 0.f};
  for (int c = 0; c < 4; ++c) {
    __syncthreads();
    #pragma unroll
    for (int r = 0; r < 8; ++r) {
      int idx = r * 256 + tid;           // 2048 16B-loads = 64 rows x 32 segs
      int row = idx >> 5, seg = idx & 31;
      int gm = m0 + row;
      size_t bufrow = (size_t)((gm & (NT - 1)) + 1) * NB + (gm >> 10);
      uint4 vv = *(const uint4*)(bufp + bufrow * NH + c * 128 + seg * 4);
      int a = row * 256 + (((seg >> 1) * 16) ^ ((row & 7) << 4)) + (seg & 1) * 8;
      uint2 hp, lp;
      hp.x = (vv.x & 0xFFFFu) | (vv.y << 16);
      hp.y = (vv.z & 0xFFFFu) | (vv.w << 16);
      lp.x = (vv.x >> 16) | (vv.y & 0xFFFF0000u);
      lp.y = (vv.z >> 16) | (vv.w & 0xFFFF0000u);
      *(uint2*)((unsigned char*)Ah + a) = hp;
      *(uint2*)((unsigned char*)Al + a) = lp;
    }
    __syncthreads();
    #pragma unroll
    for (int s = 0; s < 4; ++s) {
      int arow = w * 16 + m;
      int aoff = arow * 256 + (((s * 64) + (q * 16)) ^ ((arow & 7) << 4));
      bf16x8 ah = *(const bf16x8*)((unsigned char*)Ah + aoff);
      bf16x8 al = *(const bf16x8*)((unsigned char*)Al + aoff);
      #pragma unroll
      for (int n = 0; n < 8; ++n) {
        size_t bo = ((size_t)(n0 / 16 + n) * 64 + (c * 16 + s * 4 + q)) * 128 + m * 8;
        bf16x8 bh = *(const bf16x8*)(Wh + bo);
        bf16x8 bl = *(const bf16x8*)(Wl + bo);
        acc[n] = __builtin_amdgcn_mfma_f32_16x16x32_bf16(ah, bh, acc[n], 0, 0, 0);
        acc[n] = __builtin_amdgcn_mfma_f32_16x16x32_bf16(ah, bl, acc[n], 0, 0, 0);
        acc[n] = __builtin_amdgcn_mfma_f32_16x16x32_bf16(al, bh, acc[n], 0, 0, 0);
      }
    }
  }
  #pragma unroll
  for (int n = 0; n < 8; ++n) {
    int col = n0 + n * 16 + m;
    float bv = bias[col];
    #pragma unroll
    for (int i = 0; i < 4; ++i) {
      int mrow = m0 + w * 16 + q * 4 + i;
      out[(size_t)mrow * N + col] = acc[n][i] + bv;
    }
  }
}

__global__ void k_tail(const u32* __restrict__ bufp, float* __restrict__ out) {
  int i = blockIdx.x * blockDim.x + threadIdx.x;
  if (i < NB * NH) out[i] = unpack_hl(bufp[(size_t)NT * NB * NH + i]);
}

// ---------------- launch ----------------

extern "C" void kernel_launch(void* const* d_in, const int* in_sizes, int n_in,
                              void* d_out, int out_size, void* d_ws, size_t ws_size,
                              hipStream_t stream) {
  const int*   tokens0    = (const int*)d_in[0];
  const int*   tokens1    = (const int*)d_in[1];
  const int*   conditions = (const int*)d_in[2];
  const float* hidden     = (const float*)d_in[3];
  const float* emb0       = (const float*)d_in[4];
  const float* emb1       = (const float*)d_in[5];
  const float* W_ih       = (const float*)d_in[6];
  const float* W_hh       = (const float*)d_in[7];
  const float* b_ih       = (const float*)d_in[8];
  const float* b_hh       = (const float*)d_in[9];
  const float* dec0_W     = (const float*)d_in[10];
  const float* dec0_b     = (const float*)d_in[11];
  const float* dec1_W     = (const float*)d_in[12];
  const float* dec1_b     = (const float*)d_in[13];

  char* wsb = (char*)d_ws;
  float* proj0 = (float*)wsb;                      // 12,582,912 B
  float* proj1 = (float*)(wsb + 12582912);         //  3,145,728 B
  float* Wt_ih = (float*)(wsb + 15728640);         //  3,145,728 B (reused below)
  // gflag/items/nitems overlay Wt_ih's region: used only AFTER k_proj
  int*   gflag   = (int*)(wsb + 15728640);         // 32*16416 ints = 2,101,248 B
  int*   items   = (int*)(wsb + 17829888);         // 32*1024 ints = 131,072 B
  int*   nitems  = (int*)(wsb + 17960960);         // 32 ints
  u32*   bufp  = (u32*)(wsb + 18874368);           // 1025*32*512 u32 = 67,174,400 B
  u16*   Wfh   = (u16*)(wsb + 86048768);           //  1,572,864 B
  u16*   Wfl   = (u16*)(wsb + 87621632);           //  1,572,864 B
  u16*   d0Wh  = (u16*)(wsb + 89194496);           //  2,097,152 B
  u16*   d0Wl  = (u16*)(wsb + 91291648);           //  2,097,152 B
  u16*   d1Wh  = (u16*)(wsb + 93388800);           //    524,288 B
  u16*   d1Wl  = (u16*)(wsb + 93913088);           //    524,288 B
  int*   node_list = (int*)(wsb + 94437376);       // 32768 ints

  float* out0 = (float*)d_out;
  float* out1 = out0 + (size_t)NB * NT * NV0;
  float* outT = out1 + (size_t)NB * NT * NV1;

  // Wt_ih produced+consumed first; then its region is reused for dataflow state.
  k_transpose<<<dim3(16, 48), dim3(32, 8), 0, stream>>>(W_ih, Wt_ih);
  k_proj<<<320, 256, 0, stream>>>(emb0, emb1, Wt_ih, proj0, proj1);
  k_wsplit<<<3072, 256, 0, stream>>>(W_hh, Wfh, Wfl);
  k_wsplit_dec<<<4096, 256, 0, stream>>>(dec0_W, d0Wh, d0Wl, NV0);
  k_wsplit_dec<<<1024, 256, 0, stream>>>(dec1_W, d1Wh, d1Wl, NV1);
  k_plan<<<NB, 256, 0, stream>>>(conditions, hidden, bufp, gflag, items, nitems,
                                 node_list);

  rnn_steps<<<NCHUNK * NB, 128, 0, stream>>>(items, nitems, node_list, conditions,
                                             tokens0, tokens1, Wfh, Wfl, proj0, proj1,
                                             b_ih, b_hh, bufp, gflag);

  k_dec<<<dim3(NV0 / 128, (NB * NT) / 64), 256, 0, stream>>>(bufp, d0Wh, d0Wl, dec0_b, out0, NV0);
  k_dec<<<dim3(NV1 / 128, (NB * NT) / 64), 256, 0, stream>>>(bufp, d1Wh, d1Wl, dec1_b, out1, NV1);
  k_tail<<<64, 256, 0, stream>>>(bufp, outT);
}

// Round 15
// 2319.858 us; speedup vs baseline: 1.3553x; 1.3553x over previous
//
#include <hip/hip_runtime.h>

#define NB 32
#define NT 1024
#define NH 512
#define NE 256
#define NV0 2048
#define NV1 512
#define G3H 1536
#define NCHUNK 16       // hh chunks (32 hh x 3 gates each)
#define SENT 0xFFFFFFFFu

typedef __attribute__((ext_vector_type(8))) short bf16x8;
typedef __attribute__((ext_vector_type(4))) float f32x4;
typedef unsigned short u16;
typedef unsigned int u32;
typedef unsigned long long u64;

__device__ __forceinline__ u16 bf16_hi(float x) {
  unsigned u = __float_as_uint(x);
  unsigned r = (u + 0x7FFF + ((u >> 16) & 1)) >> 16;
  return (u16)r;
}
__device__ __forceinline__ float bf16_f(u16 h) {
  return __uint_as_float(((unsigned)h) << 16);
}
__device__ __forceinline__ u32 pack_hl(float v) {
  u16 hi = bf16_hi(v);
  u16 lo = bf16_hi(v - bf16_f(hi));
  return (u32)hi | ((u32)lo << 16);
}
__device__ __forceinline__ float unpack_hl(u32 w) {
  return bf16_f((u16)w) + bf16_f((u16)(w >> 16));
}

// ---------------- prep ----------------

// sentinel-fill state rows 1..NT (rows are written exactly once; a non-sentinel
// read IS the final value -- value-based sync, no flags). |h|<=1 so a finite
// packed value can never be 0xFFFFFFFF (hi=0xFFFF would be NaN).
__global__ void k_sent(u32* __restrict__ bufp) {
  uint4* p = (uint4*)(bufp + NB * NH);
  size_t n = (size_t)NT * NB * NH / 4;
  uint4 s = {SENT, SENT, SENT, SENT};
  for (size_t k = (size_t)blockIdx.x * blockDim.x + threadIdx.x; k < n;
       k += (size_t)gridDim.x * blockDim.x)
    p[k] = s;
}

__global__ void k_transpose(const float* __restrict__ in, float* __restrict__ out) {
  __shared__ float tile[32][33];
  int bx = blockIdx.x, by = blockIdx.y;
  int x = threadIdx.x, y = threadIdx.y;
  #pragma unroll
  for (int j = 0; j < 4; ++j)
    tile[y + j * 8][x] = in[(by * 32 + y + j * 8) * 512 + bx * 32 + x];
  __syncthreads();
  #pragma unroll
  for (int j = 0; j < 4; ++j)
    out[(bx * 32 + y + j * 8) * 1536 + by * 32 + x] = tile[x][y + j * 8];
}

__global__ __launch_bounds__(256) void k_proj(const float* __restrict__ emb0,
                                              const float* __restrict__ emb1,
                                              const float* __restrict__ Wt_ih,
                                              float* __restrict__ proj0,
                                              float* __restrict__ proj1) {
  __shared__ float a[8][NE];
  int g0 = blockIdx.x * 8;
  int tid = threadIdx.x;
  for (int i = tid; i < 8 * NE; i += 256) {
    int v = g0 + (i >> 8);
    int k = i & 255;
    a[i >> 8][k] = (v < NV0) ? emb0[v * NE + k] : emb1[(v - NV0) * NE + k];
  }
  __syncthreads();
  bool is0 = (g0 < NV0);
  int koff = is0 ? 0 : NE;
  float acc[8][6];
  #pragma unroll
  for (int v = 0; v < 8; ++v)
    #pragma unroll
    for (int j = 0; j < 6; ++j) acc[v][j] = 0.f;
  for (int k = 0; k < NE; ++k) {
    const float* wrow = Wt_ih + (size_t)(k + koff) * G3H;
    float w[6];
    #pragma unroll
    for (int j = 0; j < 6; ++j) w[j] = wrow[tid + j * 256];
    #pragma unroll
    for (int v = 0; v < 8; ++v) {
      float av = a[v][k];
      #pragma unroll
      for (int j = 0; j < 6; ++j) acc[v][j] += av * w[j];
    }
  }
  float* outp = is0 ? (proj0 + (size_t)g0 * G3H) : (proj1 + (size_t)(g0 - NV0) * G3H);
  for (int v = 0; v < 8; ++v)
    for (int j = 0; j < 6; ++j)
      outp[(size_t)v * G3H + tid + j * 256] = acc[v][j];
}

// W_hh split: tile tt = (hh>>4)*3 + g  (32 hh16-blocks x 3 gates = 96 tiles of 16x512)
__global__ void k_wsplit(const float* __restrict__ W_hh, u16* __restrict__ Wfh,
                         u16* __restrict__ Wfl) {
  int idx = blockIdx.x * blockDim.x + threadIdx.x;
  if (idx >= G3H * NH) return;
  int row = idx >> 9, k = idx & 511;
  int g = row >> 9, hh = row & 511;
  int tt = (hh >> 4) * 3 + g;
  size_t phys = ((size_t)tt * 64 + (k >> 3)) * 128 + (hh & 15) * 8 + (k & 7);
  float v = W_hh[idx];
  u16 hi = bf16_hi(v);
  Wfh[phys] = hi;
  Wfl[phys] = bf16_hi(v - bf16_f(hi));
}

__global__ void k_wsplit_dec(const float* __restrict__ W, u16* __restrict__ Wh,
                             u16* __restrict__ Wl, int R) {
  int idx = blockIdx.x * blockDim.x + threadIdx.x;
  if (idx >= R * 512) return;
  int row = idx >> 9, k = idx & 511;
  size_t phys = ((size_t)(row >> 4) * 64 + (k >> 3)) * 128 + (row & 15) * 8 + (k & 7);
  float v = W[idx];
  u16 hi = bf16_hi(v);
  Wh[phys] = hi;
  Wl[phys] = bf16_hi(v - bf16_f(hi));
}

// Fused planning: one block per batch. Computes levels, builds level-ordered
// item list (groups of <=16) + node_list, inits state row 0.
__global__ __launch_bounds__(256) void k_plan(const int* __restrict__ cond,
                                              const float* __restrict__ hidden,
                                              u32* __restrict__ bufp,
                                              int* __restrict__ items,
                                              int* __restrict__ nitems,
                                              int* __restrict__ node_list) {
  __shared__ int c_lds[NT];
  __shared__ int lvl[NT + 1];
  __shared__ int off[NT + 1];
  int b = blockIdx.x, tid = threadIdx.x;
  for (int h = tid; h < NH; h += 256) bufp[b * NH + h] = pack_hl(hidden[b * NH + h]);
  for (int i = tid; i < NT; i += 256) c_lds[i] = cond[b * NT + i];
  for (int i = tid; i <= NT; i += 256) off[i] = 0;
  __syncthreads();
  if (tid == 0) {
    lvl[0] = 0;
    for (int t = 0; t < NT; ++t) {
      int l = lvl[c_lds[t]] + 1;
      lvl[t + 1] = l;
      off[l - 1]++;                       // counts
    }
    int off0 = 0, io = 0;
    for (int p = 0; p <= NT; ++p) {
      int n = off[p];
      off[p] = off0;                      // counts -> offsets
      for (int g0 = 0; g0 < n; g0 += 16) {
        int nb = n - g0; if (nb > 16) nb = 16;
        items[b * 1024 + io++] = (p << 21) | ((b * 1024 + off0 + g0) << 6) | nb;
      }
      off0 += n;
    }
    nitems[b] = io;
    for (int t = 0; t < NT; ++t) {        // scatter (offsets become cursors)
      int p = lvl[t + 1] - 1;
      node_list[b * 1024 + off[p]++] = (b << 16) | t;
    }
  }
}

// ---------------- recurrence: per-batch level streams, VALUE-SYNC ----------------
// Grid = 16 chunks x 32 batches = 512 blocks of 128 threads (2 waves), 2 blocks/CU.
// NO FLAGS: state rows are pre-filled with sentinel 0xFFFFFFFF (impossible for
// finite packed h). Consumers spin directly on the parent-state words (relaxed
// agent-atomic u64 loads, all 16 in flight; re-load only while any half is
// sentinel). Each word transitions sentinel->final exactly once, so a
// non-sentinel read IS the correct value -- no fences, no publish, correct
// under any dispatch order / XCD mapping. Producers just store and move on.

__global__ __launch_bounds__(128, 8) void rnn_steps(
    const int* __restrict__ items, const int* __restrict__ nitems,
    const int* __restrict__ node_list, const int* __restrict__ cond,
    const int* __restrict__ tok0, const int* __restrict__ tok1,
    const u16* __restrict__ Wfh, const u16* __restrict__ Wfl,
    const float* __restrict__ proj0, const float* __restrict__ proj1,
    const float* __restrict__ b_ih, const float* __restrict__ b_hh,
    u32* __restrict__ bufp) {
  __shared__ unsigned char hds_h[16 * 1024];
  __shared__ unsigned char hds_l[16 * 1024];
  __shared__ int s_tb[16], s_par[16], s_k0[16], s_k1[16];
  int tid = threadIdx.x;
  int w = tid >> 6, lane = tid & 63, q = lane >> 4, m = lane & 15;
  int c = blockIdx.x & (NCHUNK - 1);
  int b = blockIdx.x >> 4;
  int nIt = nitems[b];
  const int* myItems = items + b * 1024;
  // wave-invariant constants
  int hb = c * 2 + w;          // hh16-block owned by this wave
  int hh = hb * 16 + m;
  float bir = b_ih[hh] + b_hh[hh];
  float biz = b_ih[NH + hh] + b_hh[NH + hh];
  float bin = b_ih[2 * NH + hh];
  float bhn = b_hh[2 * NH + hh];
  const u16* wh = Wfh + (size_t)hb * 3 * 8192;
  const u16* wl = Wfl + (size_t)hb * 3 * 8192;
  for (int j = 0; j < nIt; ++j) {
    __syncthreads();   // protect LDS from previous item (drains stores too)
    int desc = myItems[j];
    int start = (desc >> 6) & 0x7FFF;
    int nb = desc & 63;
    if (tid < 16) {
      int bb = 0, t = -1, par = 0, q0 = 0, q1 = 0;
      if (tid < nb) {
        int pk = node_list[start + tid];
        bb = pk >> 16; t = pk & 0xFFFF;
        par = cond[bb * NT + t];
        q0 = tok0[bb * NT + t];
        q1 = tok1[bb * NT + t];
      }
      s_tb[tid] = (t + 1) * NB + bb;
      s_par[tid] = par * NB + bb;
      s_k0[tid] = q0; s_k1[tid] = q1;
    }
    __syncthreads();
    // ---- gi gather (independent of parents): overlaps the state spin ----
    f32x4 aR, aZ, aN;
    float gin[4];
    #pragma unroll
    for (int i = 0; i < 4; ++i) {
      int node = q * 4 + i;
      const float* p0 = proj0 + (size_t)s_k0[node] * G3H;
      const float* p1 = proj1 + (size_t)s_k1[node] * G3H;
      aR[i] = p0[hh] + p1[hh] + bir;
      aZ[i] = p0[NH + hh] + p1[NH + hh] + biz;
      gin[i] = p0[2 * NH + hh] + p1[2 * NH + hh] + bin;
      aN[i] = bhn;
    }
    // ---- stage nb parent states: SPIN ON DATA (16 u64 in flight per thread) ----
    for (int idx = tid; idx < nb * 16; idx += 128) {
      int r = idx >> 4, seg = idx & 15;
      size_t src = (size_t)s_par[r] * NH + seg * 32;
      u64 dv[16];
      #pragma unroll
      for (int k2 = 0; k2 < 16; ++k2)
        dv[k2] = __hip_atomic_load((const u64*)&bufp[src + k2 * 2],
                                   __ATOMIC_RELAXED, __HIP_MEMORY_SCOPE_AGENT);
      for (;;) {
        bool ok = true;
        #pragma unroll
        for (int k2 = 0; k2 < 16; ++k2)
          if ((u32)dv[k2] == SENT || (u32)(dv[k2] >> 32) == SENT) ok = false;
        if (ok) break;
        __builtin_amdgcn_s_sleep(1);
        #pragma unroll
        for (int k2 = 0; k2 < 16; ++k2)
          if ((u32)dv[k2] == SENT || (u32)(dv[k2] >> 32) == SENT)
            dv[k2] = __hip_atomic_load((const u64*)&bufp[src + k2 * 2],
                                       __ATOMIC_RELAXED, __HIP_MEMORY_SCOPE_AGENT);
      }
      int swz = (r & 7) << 4;
      #pragma unroll
      for (int k2 = 0; k2 < 16; ++k2) {
        u32 e0 = (u32)dv[k2], e1 = (u32)(dv[k2] >> 32);
        int wi = seg * 32 + k2 * 2;
        int a = r * 1024 + (((wi >> 3) * 16) ^ swz) + ((2 * wi) & 15);
        *(u32*)(hds_h + a) = (e0 & 0xFFFFu) | (e1 << 16);
        *(u32*)(hds_l + a) = (e0 >> 16) | (e1 & 0xFFFF0000u);
      }
    }
    __syncthreads();
    // ---- MFMA: wave owns hb = c*2+w, 3 gates, 16 nodes, K=512, 3-split ----
    #pragma unroll 4
    for (int s = 0; s < 16; ++s) {
      int ab = m * 1024 + (((s * 64) + (q * 16)) ^ ((m & 7) << 4));
      bf16x8 ah = *(const bf16x8*)(hds_h + ab);
      bf16x8 al = *(const bf16x8*)(hds_l + ab);
      int koff = (s * 4 + q) * 128 + m * 8;
      bf16x8 bh0 = *(const bf16x8*)(wh + koff);
      bf16x8 bl0 = *(const bf16x8*)(wl + koff);
      bf16x8 bh1 = *(const bf16x8*)(wh + 8192 + koff);
      bf16x8 bl1 = *(const bf16x8*)(wl + 8192 + koff);
      bf16x8 bh2 = *(const bf16x8*)(wh + 16384 + koff);
      bf16x8 bl2 = *(const bf16x8*)(wl + 16384 + koff);
      aR = __builtin_amdgcn_mfma_f32_16x16x32_bf16(ah, bh0, aR, 0, 0, 0);
      aR = __builtin_amdgcn_mfma_f32_16x16x32_bf16(ah, bl0, aR, 0, 0, 0);
      aR = __builtin_amdgcn_mfma_f32_16x16x32_bf16(al, bh0, aR, 0, 0, 0);
      aZ = __builtin_amdgcn_mfma_f32_16x16x32_bf16(ah, bh1, aZ, 0, 0, 0);
      aZ = __builtin_amdgcn_mfma_f32_16x16x32_bf16(ah, bl1, aZ, 0, 0, 0);
      aZ = __builtin_amdgcn_mfma_f32_16x16x32_bf16(al, bh1, aZ, 0, 0, 0);
      aN = __builtin_amdgcn_mfma_f32_16x16x32_bf16(ah, bh2, aN, 0, 0, 0);
      aN = __builtin_amdgcn_mfma_f32_16x16x32_bf16(ah, bl2, aN, 0, 0, 0);
      aN = __builtin_amdgcn_mfma_f32_16x16x32_bf16(al, bh2, aN, 0, 0, 0);
    }
    // ---- in-register GRU epilogue; packed u32 agent-atomic state stores ----
    // (no drain/publish: the data IS the flag)
    #pragma unroll
    for (int i = 0; i < 4; ++i) {
      int node = q * 4 + i;
      if (node < nb) {
        float rg = 1.f / (1.f + __expf(-aR[i]));
        float zg = 1.f / (1.f + __expf(-aZ[i]));
        float nn = 1.f - 2.f / (1.f + __expf(2.f * (gin[i] + rg * aN[i])));
        int hofs = node * 1024 + ((hh * 2) ^ ((node & 7) << 4));
        float hp = bf16_f(*(const u16*)(hds_h + hofs)) + bf16_f(*(const u16*)(hds_l + hofs));
        float hn = (1.f - zg) * nn + zg * hp;
        __hip_atomic_store(&bufp[(size_t)s_tb[node] * NH + hh], pack_hl(hn),
                           __ATOMIC_RELAXED, __HIP_MEMORY_SCOPE_AGENT);
      }
    }
  }
}

// ---------------- decode GEMM: MFMA bf16 3-split, 64x128 tiles ----------------

__global__ __launch_bounds__(256) void k_dec(const u32* __restrict__ bufp,
                                             const u16* __restrict__ Wh,
                                             const u16* __restrict__ Wl,
                                             const float* __restrict__ bias,
                                             float* __restrict__ out, int N) {
  __shared__ u16 Ah[64 * 128];
  __shared__ u16 Al[64 * 128];
  int tid = threadIdx.x;
  int w = tid >> 6, lane = tid & 63, q = lane >> 4, m = lane & 15;
  int n0 = blockIdx.x * 128, m0 = blockIdx.y * 64;
  f32x4 acc[8];
  #pragma unroll
  for (int n = 0; n < 8; ++n) acc[n] = (f32x4){0.f, 0.f, 0.f, 0.f};
  for (int c = 0; c < 4; ++c) {
    __syncthreads();
    #pragma unroll
    for (int r = 0; r < 8; ++r) {
      int idx = r * 256 + tid;           // 2048 16B-loads = 64 rows x 32 segs
      int row = idx >> 5, seg = idx & 31;
      int gm = m0 + row;
      size_t bufrow = (size_t)((gm & (NT - 1)) + 1) * NB + (gm >> 10);
      uint4 vv = *(const uint4*)(bufp + bufrow * NH + c * 128 + seg * 4);
      int a = row * 256 + (((seg >> 1) * 16) ^ ((row & 7) << 4)) + (seg & 1) * 8;
      uint2 hp, lp;
      hp.x = (vv.x & 0xFFFFu) | (vv.y << 16);
      hp.y = (vv.z & 0xFFFFu) | (vv.w << 16);
      lp.x = (vv.x >> 16) | (vv.y & 0xFFFF0000u);
      lp.y = (vv.z >> 16) | (vv.w & 0xFFFF0000u);
      *(uint2*)((unsigned char*)Ah + a) = hp;
      *(uint2*)((unsigned char*)Al + a) = lp;
    }
    __syncthreads();
    #pragma unroll
    for (int s = 0; s < 4; ++s) {
      int arow = w * 16 + m;
      int aoff = arow * 256 + (((s * 64) + (q * 16)) ^ ((arow & 7) << 4));
      bf16x8 ah = *(const bf16x8*)((unsigned char*)Ah + aoff);
      bf16x8 al = *(const bf16x8*)((unsigned char*)Al + aoff);
      #pragma unroll
      for (int n = 0; n < 8; ++n) {
        size_t bo = ((size_t)(n0 / 16 + n) * 64 + (c * 16 + s * 4 + q)) * 128 + m * 8;
        bf16x8 bh = *(const bf16x8*)(Wh + bo);
        bf16x8 bl = *(const bf16x8*)(Wl + bo);
        acc[n] = __builtin_amdgcn_mfma_f32_16x16x32_bf16(ah, bh, acc[n], 0, 0, 0);
        acc[n] = __builtin_amdgcn_mfma_f32_16x16x32_bf16(ah, bl, acc[n], 0, 0, 0);
        acc[n] = __builtin_amdgcn_mfma_f32_16x16x32_bf16(al, bh, acc[n], 0, 0, 0);
      }
    }
  }
  #pragma unroll
  for (int n = 0; n < 8; ++n) {
    int col = n0 + n * 16 + m;
    float bv = bias[col];
    #pragma unroll
    for (int i = 0; i < 4; ++i) {
      int mrow = m0 + w * 16 + q * 4 + i;
      out[(size_t)mrow * N + col] = acc[n][i] + bv;
    }
  }
}

__global__ void k_tail(const u32* __restrict__ bufp, float* __restrict__ out) {
  int i = blockIdx.x * blockDim.x + threadIdx.x;
  if (i < NB * NH) out[i] = unpack_hl(bufp[(size_t)NT * NB * NH + i]);
}

// ---------------- launch ----------------

extern "C" void kernel_launch(void* const* d_in, const int* in_sizes, int n_in,
                              void* d_out, int out_size, void* d_ws, size_t ws_size,
                              hipStream_t stream) {
  const int*   tokens0    = (const int*)d_in[0];
  const int*   tokens1    = (const int*)d_in[1];
  const int*   conditions = (const int*)d_in[2];
  const float* hidden     = (const float*)d_in[3];
  const float* emb0       = (const float*)d_in[4];
  const float* emb1       = (const float*)d_in[5];
  const float* W_ih       = (const float*)d_in[6];
  const float* W_hh       = (const float*)d_in[7];
  const float* b_ih       = (const float*)d_in[8];
  const float* b_hh       = (const float*)d_in[9];
  const float* dec0_W     = (const float*)d_in[10];
  const float* dec0_b     = (const float*)d_in[11];
  const float* dec1_W     = (const float*)d_in[12];
  const float* dec1_b     = (const float*)d_in[13];

  char* wsb = (char*)d_ws;
  float* proj0 = (float*)wsb;                      // 12,582,912 B
  float* proj1 = (float*)(wsb + 12582912);         //  3,145,728 B
  float* Wt_ih = (float*)(wsb + 15728640);         //  3,145,728 B (reused below)
  // items/nitems overlay Wt_ih's region: used only AFTER k_proj
  int*   items   = (int*)(wsb + 15728640);         // 32*1024 ints = 131,072 B
  int*   nitems  = (int*)(wsb + 15859712);         // 32 ints
  u32*   bufp  = (u32*)(wsb + 18874368);           // 1025*32*512 u32 = 67,174,400 B
  u16*   Wfh   = (u16*)(wsb + 86048768);           //  1,572,864 B
  u16*   Wfl   = (u16*)(wsb + 87621632);           //  1,572,864 B
  u16*   d0Wh  = (u16*)(wsb + 89194496);           //  2,097,152 B
  u16*   d0Wl  = (u16*)(wsb + 91291648);           //  2,097,152 B
  u16*   d1Wh  = (u16*)(wsb + 93388800);           //    524,288 B
  u16*   d1Wl  = (u16*)(wsb + 93913088);           //    524,288 B
  int*   node_list = (int*)(wsb + 94437376);       // 32768 ints

  float* out0 = (float*)d_out;
  float* out1 = out0 + (size_t)NB * NT * NV0;
  float* outT = out1 + (size_t)NB * NT * NV1;

  // Wt_ih produced+consumed first; then its region is reused for dataflow state.
  k_transpose<<<dim3(16, 48), dim3(32, 8), 0, stream>>>(W_ih, Wt_ih);
  k_proj<<<320, 256, 0, stream>>>(emb0, emb1, Wt_ih, proj0, proj1);
  k_sent<<<2048, 256, 0, stream>>>(bufp);
  k_wsplit<<<3072, 256, 0, stream>>>(W_hh, Wfh, Wfl);
  k_wsplit_dec<<<4096, 256, 0, stream>>>(dec0_W, d0Wh, d0Wl, NV0);
  k_wsplit_dec<<<1024, 256, 0, stream>>>(dec1_W, d1Wh, d1Wl, NV1);
  k_plan<<<NB, 256, 0, stream>>>(conditions, hidden, bufp, items, nitems, node_list);

  rnn_steps<<<NCHUNK * NB, 128, 0, stream>>>(items, nitems, node_list, conditions,
                                             tokens0, tokens1, Wfh, Wfl, proj0, proj1,
                                             b_ih, b_hh, bufp);

  k_dec<<<dim3(NV0 / 128, (NB * NT) / 64), 256, 0, stream>>>(bufp, d0Wh, d0Wl, dec0_b, out0, NV0);
  k_dec<<<dim3(NV1 / 128, (NB * NT) / 64), 256, 0, stream>>>(bufp, d1Wh, d1Wl, dec1_b, out1, NV1);
  k_tail<<<64, 256, 0, stream>>>(bufp, outT);
}

// Round 16
// 2318.673 us; speedup vs baseline: 1.3560x; 1.0005x over previous
//
#include <hip/hip_runtime.h>

#define NB 32
#define NT 1024
#define NH 512
#define NE 256
#define NV0 2048
#define NV1 512
#define G3H 1536
#define NCHUNK 16       // hh chunks (32 hh x 3 gates each)
#define SENT 0xFFFFFFFFu

typedef __attribute__((ext_vector_type(8))) short bf16x8;
typedef __attribute__((ext_vector_type(4))) float f32x4;
typedef unsigned short u16;
typedef unsigned int u32;
typedef unsigned long long u64;

__device__ __forceinline__ u16 bf16_hi(float x) {
  unsigned u = __float_as_uint(x);
  unsigned r = (u + 0x7FFF + ((u >> 16) & 1)) >> 16;
  return (u16)r;
}
__device__ __forceinline__ float bf16_f(u16 h) {
  return __uint_as_float(((unsigned)h) << 16);
}
__device__ __forceinline__ u32 pack_hl(float v) {
  u16 hi = bf16_hi(v);
  u16 lo = bf16_hi(v - bf16_f(hi));
  return (u32)hi | ((u32)lo << 16);
}
__device__ __forceinline__ float unpack_hl(u32 w) {
  return bf16_f((u16)w) + bf16_f((u16)(w >> 16));
}

// ---------------- prep ----------------

// sentinel-fill state rows 1..NT (each row written exactly once; a non-sentinel
// read IS the final value -- value-based sync). |h|<=1 so finite packed h can
// never be 0xFFFFFFFF (hi=0xFFFF would be NaN).
__global__ void k_sent(u32* __restrict__ bufp) {
  uint4* p = (uint4*)(bufp + NB * NH);
  size_t n = (size_t)NT * NB * NH / 4;
  uint4 s = {SENT, SENT, SENT, SENT};
  for (size_t k = (size_t)blockIdx.x * blockDim.x + threadIdx.x; k < n;
       k += (size_t)gridDim.x * blockDim.x)
    p[k] = s;
}

__global__ void k_transpose(const float* __restrict__ in, float* __restrict__ out) {
  __shared__ float tile[32][33];
  int bx = blockIdx.x, by = blockIdx.y;
  int x = threadIdx.x, y = threadIdx.y;
  #pragma unroll
  for (int j = 0; j < 4; ++j)
    tile[y + j * 8][x] = in[(by * 32 + y + j * 8) * 512 + bx * 32 + x];
  __syncthreads();
  #pragma unroll
  for (int j = 0; j < 4; ++j)
    out[(bx * 32 + y + j * 8) * 1536 + by * 32 + x] = tile[x][y + j * 8];
}

__global__ __launch_bounds__(256) void k_proj(const float* __restrict__ emb0,
                                              const float* __restrict__ emb1,
                                              const float* __restrict__ Wt_ih,
                                              float* __restrict__ proj0,
                                              float* __restrict__ proj1) {
  __shared__ float a[8][NE];
  int g0 = blockIdx.x * 8;
  int tid = threadIdx.x;
  for (int i = tid; i < 8 * NE; i += 256) {
    int v = g0 + (i >> 8);
    int k = i & 255;
    a[i >> 8][k] = (v < NV0) ? emb0[v * NE + k] : emb1[(v - NV0) * NE + k];
  }
  __syncthreads();
  bool is0 = (g0 < NV0);
  int koff = is0 ? 0 : NE;
  float acc[8][6];
  #pragma unroll
  for (int v = 0; v < 8; ++v)
    #pragma unroll
    for (int j = 0; j < 6; ++j) acc[v][j] = 0.f;
  for (int k = 0; k < NE; ++k) {
    const float* wrow = Wt_ih + (size_t)(k + koff) * G3H;
    float w[6];
    #pragma unroll
    for (int j = 0; j < 6; ++j) w[j] = wrow[tid + j * 256];
    #pragma unroll
    for (int v = 0; v < 8; ++v) {
      float av = a[v][k];
      #pragma unroll
      for (int j = 0; j < 6; ++j) acc[v][j] += av * w[j];
    }
  }
  float* outp = is0 ? (proj0 + (size_t)g0 * G3H) : (proj1 + (size_t)(g0 - NV0) * G3H);
  for (int v = 0; v < 8; ++v)
    for (int j = 0; j < 6; ++j)
      outp[(size_t)v * G3H + tid + j * 256] = acc[v][j];
}

// W_hh split: tile tt = (hh>>4)*3 + g  (32 hh16-blocks x 3 gates = 96 tiles of 16x512)
__global__ void k_wsplit(const float* __restrict__ W_hh, u16* __restrict__ Wfh,
                         u16* __restrict__ Wfl) {
  int idx = blockIdx.x * blockDim.x + threadIdx.x;
  if (idx >= G3H * NH) return;
  int row = idx >> 9, k = idx & 511;
  int g = row >> 9, hh = row & 511;
  int tt = (hh >> 4) * 3 + g;
  size_t phys = ((size_t)tt * 64 + (k >> 3)) * 128 + (hh & 15) * 8 + (k & 7);
  float v = W_hh[idx];
  u16 hi = bf16_hi(v);
  Wfh[phys] = hi;
  Wfl[phys] = bf16_hi(v - bf16_f(hi));
}

__global__ void k_wsplit_dec(const float* __restrict__ W, u16* __restrict__ Wh,
                             u16* __restrict__ Wl, int R) {
  int idx = blockIdx.x * blockDim.x + threadIdx.x;
  if (idx >= R * 512) return;
  int row = idx >> 9, k = idx & 511;
  size_t phys = ((size_t)(row >> 4) * 64 + (k >> 3)) * 128 + (row & 15) * 8 + (k & 7);
  float v = W[idx];
  u16 hi = bf16_hi(v);
  Wh[phys] = hi;
  Wl[phys] = bf16_hi(v - bf16_f(hi));
}

// Fused planning: one block per batch. Serial pass computes levels, item list,
// and each node's slot position; PARALLEL pass pre-resolves per-node metadata:
// meta2[pos] = { tb | k0<<17, par | k1<<17 }  (tb,par < 2^17; k0<2^11; k1<2^9).
// rnn_steps then needs NO node_list/cond/tok chain -- one int2 load per use.
__global__ __launch_bounds__(256) void k_plan(const int* __restrict__ cond,
                                              const int* __restrict__ tok0,
                                              const int* __restrict__ tok1,
                                              const float* __restrict__ hidden,
                                              u32* __restrict__ bufp,
                                              int* __restrict__ items,
                                              int* __restrict__ nitems,
                                              int2* __restrict__ meta2) {
  __shared__ int c_lds[NT];
  __shared__ int lvl[NT + 1];
  __shared__ int off[NT + 1];
  __shared__ int pos_lds[NT];
  int b = blockIdx.x, tid = threadIdx.x;
  for (int h = tid; h < NH; h += 256) bufp[b * NH + h] = pack_hl(hidden[b * NH + h]);
  for (int i = tid; i < NT; i += 256) c_lds[i] = cond[b * NT + i];
  for (int i = tid; i <= NT; i += 256) off[i] = 0;
  __syncthreads();
  if (tid == 0) {
    lvl[0] = 0;
    for (int t = 0; t < NT; ++t) {
      int l = lvl[c_lds[t]] + 1;
      lvl[t + 1] = l;
      off[l - 1]++;                       // counts
    }
    int off0 = 0, io = 0;
    for (int p = 0; p <= NT; ++p) {
      int n = off[p];
      off[p] = off0;                      // counts -> offsets
      for (int g0 = 0; g0 < n; g0 += 16) {
        int nb = n - g0; if (nb > 16) nb = 16;
        items[b * 1024 + io++] = ((b * 1024 + off0 + g0) << 6) | nb;
      }
      off0 += n;
    }
    nitems[b] = io;
    for (int t = 0; t < NT; ++t) {        // node -> slot position
      int p = lvl[t + 1] - 1;
      pos_lds[t] = off[p]++;
    }
  }
  __syncthreads();
  for (int t = tid; t < NT; t += 256) {
    int tb = (t + 1) * NB + b;
    int par = c_lds[t] * NB + b;
    int k0 = tok0[b * NT + t];
    int k1 = tok1[b * NT + t];
    int2 v;
    v.x = tb | (k0 << 17);
    v.y = par | (k1 << 17);
    meta2[b * 1024 + pos_lds[t]] = v;
  }
}

// ---------------- recurrence: per-batch level streams, VALUE-SYNC, direct meta ----------------
// Grid = 16 chunks x 32 batches = 512 blocks of 128 threads (2 waves), 2 blocks/CU.
// NO FLAGS (r15-proven): consumers spin directly on sentinel-filled parent-state
// words (relaxed agent-atomic u64 loads); non-sentinel read IS the final value.
// NO metadata phase: each thread loads pre-resolved meta2 words directly from
// L2 (broadcast within the item's 128B region). Only 2 barriers/item: LDS
// protect (pre-stage) and stage->MFMA. Producers store and move on.

__global__ __launch_bounds__(128, 4) void rnn_steps(
    const int* __restrict__ items, const int* __restrict__ nitems,
    const int2* __restrict__ meta2,
    const u16* __restrict__ Wfh, const u16* __restrict__ Wfl,
    const float* __restrict__ proj0, const float* __restrict__ proj1,
    const float* __restrict__ b_ih, const float* __restrict__ b_hh,
    u32* __restrict__ bufp) {
  __shared__ unsigned char hds_h[16 * 1024];
  __shared__ unsigned char hds_l[16 * 1024];
  int tid = threadIdx.x;
  int w = tid >> 6, lane = tid & 63, q = lane >> 4, m = lane & 15;
  int c = blockIdx.x & (NCHUNK - 1);
  int b = blockIdx.x >> 4;
  int nIt = nitems[b];
  const int* myItems = items + b * 1024;
  // wave-invariant constants
  int hb = c * 2 + w;          // hh16-block owned by this wave
  int hh = hb * 16 + m;
  float bir = b_ih[hh] + b_hh[hh];
  float biz = b_ih[NH + hh] + b_hh[NH + hh];
  float bin = b_ih[2 * NH + hh];
  float bhn = b_hh[2 * NH + hh];
  const u16* wh = Wfh + (size_t)hb * 3 * 8192;
  const u16* wl = Wfl + (size_t)hb * 3 * 8192;
  for (int j = 0; j < nIt; ++j) {
    int desc = myItems[j];
    int start = (desc >> 6) & 0x7FFF;
    int nb = desc & 63;
    // ---- direct meta loads for this thread's 4 nodes (gi + store targets) ----
    int2 md[4];
    #pragma unroll
    for (int i = 0; i < 4; ++i) {
      int node = q * 4 + i;
      md[i] = meta2[start + (node < nb ? node : 0)];
    }
    // ---- gi gather (independent of parents): overlaps everything below ----
    f32x4 aR, aZ, aN;
    float gin[4];
    #pragma unroll
    for (int i = 0; i < 4; ++i) {
      const float* p0 = proj0 + (size_t)(((u32)md[i].x) >> 17) * G3H;
      const float* p1 = proj1 + (size_t)(((u32)md[i].y) >> 17) * G3H;
      aR[i] = p0[hh] + p1[hh] + bir;
      aZ[i] = p0[NH + hh] + p1[NH + hh] + biz;
      gin[i] = p0[2 * NH + hh] + p1[2 * NH + hh] + bin;
      aN[i] = bhn;
    }
    __syncthreads();   // LDS protect: previous item's MFMA reads complete
    // ---- stage nb parent states: SPIN ON DATA (16 u64 in flight per thread) ----
    for (int idx = tid; idx < nb * 16; idx += 128) {
      int r = idx >> 4, seg = idx & 15;
      int par = meta2[start + r].y & 0x1FFFF;
      size_t src = (size_t)par * NH + seg * 32;
      u64 dv[16];
      #pragma unroll
      for (int k2 = 0; k2 < 16; ++k2)
        dv[k2] = __hip_atomic_load((const u64*)&bufp[src + k2 * 2],
                                   __ATOMIC_RELAXED, __HIP_MEMORY_SCOPE_AGENT);
      for (;;) {
        bool ok = true;
        #pragma unroll
        for (int k2 = 0; k2 < 16; ++k2)
          if ((u32)dv[k2] == SENT || (u32)(dv[k2] >> 32) == SENT) ok = false;
        if (ok) break;
        __builtin_amdgcn_s_sleep(1);
        #pragma unroll
        for (int k2 = 0; k2 < 16; ++k2)
          if ((u32)dv[k2] == SENT || (u32)(dv[k2] >> 32) == SENT)
            dv[k2] = __hip_atomic_load((const u64*)&bufp[src + k2 * 2],
                                       __ATOMIC_RELAXED, __HIP_MEMORY_SCOPE_AGENT);
      }
      int swz = (r & 7) << 4;
      #pragma unroll
      for (int k2 = 0; k2 < 16; ++k2) {
        u32 e0 = (u32)dv[k2], e1 = (u32)(dv[k2] >> 32);
        int wi = seg * 32 + k2 * 2;
        int a = r * 1024 + (((wi >> 3) * 16) ^ swz) + ((2 * wi) & 15);
        *(u32*)(hds_h + a) = (e0 & 0xFFFFu) | (e1 << 16);
        *(u32*)(hds_l + a) = (e0 >> 16) | (e1 & 0xFFFF0000u);
      }
    }
    __syncthreads();
    // ---- MFMA: wave owns hb = c*2+w, 3 gates, 16 nodes, K=512, 3-split ----
    #pragma unroll 4
    for (int s = 0; s < 16; ++s) {
      int ab = m * 1024 + (((s * 64) + (q * 16)) ^ ((m & 7) << 4));
      bf16x8 ah = *(const bf16x8*)(hds_h + ab);
      bf16x8 al = *(const bf16x8*)(hds_l + ab);
      int koff = (s * 4 + q) * 128 + m * 8;
      bf16x8 bh0 = *(const bf16x8*)(wh + koff);
      bf16x8 bl0 = *(const bf16x8*)(wl + koff);
      bf16x8 bh1 = *(const bf16x8*)(wh + 8192 + koff);
      bf16x8 bl1 = *(const bf16x8*)(wl + 8192 + koff);
      bf16x8 bh2 = *(const bf16x8*)(wh + 16384 + koff);
      bf16x8 bl2 = *(const bf16x8*)(wl + 16384 + koff);
      aR = __builtin_amdgcn_mfma_f32_16x16x32_bf16(ah, bh0, aR, 0, 0, 0);
      aR = __builtin_amdgcn_mfma_f32_16x16x32_bf16(ah, bl0, aR, 0, 0, 0);
      aR = __builtin_amdgcn_mfma_f32_16x16x32_bf16(al, bh0, aR, 0, 0, 0);
      aZ = __builtin_amdgcn_mfma_f32_16x16x32_bf16(ah, bh1, aZ, 0, 0, 0);
      aZ = __builtin_amdgcn_mfma_f32_16x16x32_bf16(ah, bl1, aZ, 0, 0, 0);
      aZ = __builtin_amdgcn_mfma_f32_16x16x32_bf16(al, bh1, aZ, 0, 0, 0);
      aN = __builtin_amdgcn_mfma_f32_16x16x32_bf16(ah, bh2, aN, 0, 0, 0);
      aN = __builtin_amdgcn_mfma_f32_16x16x32_bf16(ah, bl2, aN, 0, 0, 0);
      aN = __builtin_amdgcn_mfma_f32_16x16x32_bf16(al, bh2, aN, 0, 0, 0);
    }
    // ---- in-register GRU epilogue; packed u32 agent-atomic state stores ----
    // (no drain/publish: the data IS the flag)
    #pragma unroll
    for (int i = 0; i < 4; ++i) {
      int node = q * 4 + i;
      if (node < nb) {
        float rg = 1.f / (1.f + __expf(-aR[i]));
        float zg = 1.f / (1.f + __expf(-aZ[i]));
        float nn = 1.f - 2.f / (1.f + __expf(2.f * (gin[i] + rg * aN[i])));
        int hofs = node * 1024 + ((hh * 2) ^ ((node & 7) << 4));
        float hp = bf16_f(*(const u16*)(hds_h + hofs)) + bf16_f(*(const u16*)(hds_l + hofs));
        float hn = (1.f - zg) * nn + zg * hp;
        __hip_atomic_store(&bufp[(size_t)(md[i].x & 0x1FFFF) * NH + hh], pack_hl(hn),
                           __ATOMIC_RELAXED, __HIP_MEMORY_SCOPE_AGENT);
      }
    }
  }
}

// ---------------- decode GEMM: MFMA bf16 3-split, 64x128 tiles ----------------

__global__ __launch_bounds__(256) void k_dec(const u32* __restrict__ bufp,
                                             const u16* __restrict__ Wh,
                                             const u16* __restrict__ Wl,
                                             const float* __restrict__ bias,
                                             float* __restrict__ out, int N) {
  __shared__ u16 Ah[64 * 128];
  __shared__ u16 Al[64 * 128];
  int tid = threadIdx.x;
  int w = tid >> 6, lane = tid & 63, q = lane >> 4, m = lane & 15;
  int n0 = blockIdx.x * 128, m0 = blockIdx.y * 64;
  f32x4 acc[8];
  #pragma unroll
  for (int n = 0; n < 8; ++n) acc[n] = (f32x4){0.f, 0.f, 0.f, 0.f};
  for (int c = 0; c < 4; ++c) {
    __syncthreads();
    #pragma unroll
    for (int r = 0; r < 8; ++r) {
      int idx = r * 256 + tid;           // 2048 16B-loads = 64 rows x 32 segs
      int row = idx >> 5, seg = idx & 31;
      int gm = m0 + row;
      size_t bufrow = (size_t)((gm & (NT - 1)) + 1) * NB + (gm >> 10);
      uint4 vv = *(const uint4*)(bufp + bufrow * NH + c * 128 + seg * 4);
      int a = row * 256 + (((seg >> 1) * 16) ^ ((row & 7) << 4)) + (seg & 1) * 8;
      uint2 hp, lp;
      hp.x = (vv.x & 0xFFFFu) | (vv.y << 16);
      hp.y = (vv.z & 0xFFFFu) | (vv.w << 16);
      lp.x = (vv.x >> 16) | (vv.y & 0xFFFF0000u);
      lp.y = (vv.z >> 16) | (vv.w & 0xFFFF0000u);
      *(uint2*)((unsigned char*)Ah + a) = hp;
      *(uint2*)((unsigned char*)Al + a) = lp;
    }
    __syncthreads();
    #pragma unroll
    for (int s = 0; s < 4; ++s) {
      int arow = w * 16 + m;
      int aoff = arow * 256 + (((s * 64) + (q * 16)) ^ ((arow & 7) << 4));
      bf16x8 ah = *(const bf16x8*)((unsigned char*)Ah + aoff);
      bf16x8 al = *(const bf16x8*)((unsigned char*)Al + aoff);
      #pragma unroll
      for (int n = 0; n < 8; ++n) {
        size_t bo = ((size_t)(n0 / 16 + n) * 64 + (c * 16 + s * 4 + q)) * 128 + m * 8;
        bf16x8 bh = *(const bf16x8*)(Wh + bo);
        bf16x8 bl = *(const bf16x8*)(Wl + bo);
        acc[n] = __builtin_amdgcn_mfma_f32_16x16x32_bf16(ah, bh, acc[n], 0, 0, 0);
        acc[n] = __builtin_amdgcn_mfma_f32_16x16x32_bf16(ah, bl, acc[n], 0, 0, 0);
        acc[n] = __builtin_amdgcn_mfma_f32_16x16x32_bf16(al, bh, acc[n], 0, 0, 0);
      }
    }
  }
  #pragma unroll
  for (int n = 0; n < 8; ++n) {
    int col = n0 + n * 16 + m;
    float bv = bias[col];
    #pragma unroll
    for (int i = 0; i < 4; ++i) {
      int mrow = m0 + w * 16 + q * 4 + i;
      out[(size_t)mrow * N + col] = acc[n][i] + bv;
    }
  }
}

__global__ void k_tail(const u32* __restrict__ bufp, float* __restrict__ out) {
  int i = blockIdx.x * blockDim.x + threadIdx.x;
  if (i < NB * NH) out[i] = unpack_hl(bufp[(size_t)NT * NB * NH + i]);
}

// ---------------- launch ----------------

extern "C" void kernel_launch(void* const* d_in, const int* in_sizes, int n_in,
                              void* d_out, int out_size, void* d_ws, size_t ws_size,
                              hipStream_t stream) {
  const int*   tokens0    = (const int*)d_in[0];
  const int*   tokens1    = (const int*)d_in[1];
  const int*   conditions = (const int*)d_in[2];
  const float* hidden     = (const float*)d_in[3];
  const float* emb0       = (const float*)d_in[4];
  const float* emb1       = (const float*)d_in[5];
  const float* W_ih       = (const float*)d_in[6];
  const float* W_hh       = (const float*)d_in[7];
  const float* b_ih       = (const float*)d_in[8];
  const float* b_hh       = (const float*)d_in[9];
  const float* dec0_W     = (const float*)d_in[10];
  const float* dec0_b     = (const float*)d_in[11];
  const float* dec1_W     = (const float*)d_in[12];
  const float* dec1_b     = (const float*)d_in[13];

  char* wsb = (char*)d_ws;
  float* proj0 = (float*)wsb;                      // 12,582,912 B
  float* proj1 = (float*)(wsb + 12582912);         //  3,145,728 B
  float* Wt_ih = (float*)(wsb + 15728640);         //  3,145,728 B (reused below)
  // items/nitems/meta2 overlay Wt_ih's region: used only AFTER k_proj
  int*   items   = (int*)(wsb + 15728640);         // 32*1024 ints = 131,072 B
  int*   nitems  = (int*)(wsb + 15859712);         // 32 ints (pad to 256B)
  int2*  meta2   = (int2*)(wsb + 15859968);        // 32*1024 int2 = 262,144 B
  u32*   bufp  = (u32*)(wsb + 18874368);           // 1025*32*512 u32 = 67,174,400 B
  u16*   Wfh   = (u16*)(wsb + 86048768);           //  1,572,864 B
  u16*   Wfl   = (u16*)(wsb + 87621632);           //  1,572,864 B
  u16*   d0Wh  = (u16*)(wsb + 89194496);           //  2,097,152 B
  u16*   d0Wl  = (u16*)(wsb + 91291648);           //  2,097,152 B
  u16*   d1Wh  = (u16*)(wsb + 93388800);           //    524,288 B
  u16*   d1Wl  = (u16*)(wsb + 93913088);           //    524,288 B

  float* out0 = (float*)d_out;
  float* out1 = out0 + (size_t)NB * NT * NV0;
  float* outT = out1 + (size_t)NB * NT * NV1;

  // Wt_ih produced+consumed first; then its region is reused for dataflow state.
  k_transpose<<<dim3(16, 48), dim3(32, 8), 0, stream>>>(W_ih, Wt_ih);
  k_proj<<<320, 256, 0, stream>>>(emb0, emb1, Wt_ih, proj0, proj1);
  k_sent<<<2048, 256, 0, stream>>>(bufp);
  k_wsplit<<<3072, 256, 0, stream>>>(W_hh, Wfh, Wfl);
  k_wsplit_dec<<<4096, 256, 0, stream>>>(dec0_W, d0Wh, d0Wl, NV0);
  k_wsplit_dec<<<1024, 256, 0, stream>>>(dec1_W, d1Wh, d1Wl, NV1);
  k_plan<<<NB, 256, 0, stream>>>(conditions, tokens0, tokens1, hidden, bufp,
                                 items, nitems, meta2);

  rnn_steps<<<NCHUNK * NB, 128, 0, stream>>>(items, nitems, meta2, Wfh, Wfl,
                                             proj0, proj1, b_ih, b_hh, bufp);

  k_dec<<<dim3(NV0 / 128, (NB * NT) / 64), 256, 0, stream>>>(bufp, d0Wh, d0Wl, dec0_b, out0, NV0);
  k_dec<<<dim3(NV1 / 128, (NB * NT) / 64), 256, 0, stream>>>(bufp, d1Wh, d1Wl, dec1_b, out1, NV1);
  k_tail<<<64, 256, 0, stream>>>(bufp, outT);
}

// Round 17
// 1690.147 us; speedup vs baseline: 1.8602x; 1.3719x over previous
//
#include <hip/hip_runtime.h>

#define NB 32
#define NT 1024
#define NH 512
#define NE 256
#define NV0 2048
#define NV1 512
#define G3H 1536
#define NCHUNK 16       // hh chunks (32 hh x 3 gates each)
#define SENT 0xFFFFFFFFu

typedef __attribute__((ext_vector_type(8))) short bf16x8;
typedef __attribute__((ext_vector_type(4))) float f32x4;
typedef unsigned short u16;
typedef unsigned int u32;
typedef unsigned long long u64;

__device__ __forceinline__ u16 bf16_hi(float x) {
  unsigned u = __float_as_uint(x);
  unsigned r = (u + 0x7FFF + ((u >> 16) & 1)) >> 16;
  return (u16)r;
}
__device__ __forceinline__ float bf16_f(u16 h) {
  return __uint_as_float(((unsigned)h) << 16);
}
__device__ __forceinline__ u32 pack_hl(float v) {
  u16 hi = bf16_hi(v);
  u16 lo = bf16_hi(v - bf16_f(hi));
  return (u32)hi | ((u32)lo << 16);
}
__device__ __forceinline__ float unpack_hl(u32 w) {
  return bf16_f((u16)w) + bf16_f((u16)(w >> 16));
}

// ---------------- prep ----------------

// sentinel-fill state rows 1..NT (each row written exactly once; a non-sentinel
// read IS the final value -- value-based sync). |h|<=1 so finite packed h can
// never be 0xFFFFFFFF (hi=0xFFFF would be NaN).
__global__ void k_sent(u32* __restrict__ bufp) {
  uint4* p = (uint4*)(bufp + NB * NH);
  size_t n = (size_t)NT * NB * NH / 4;
  uint4 s = {SENT, SENT, SENT, SENT};
  for (size_t k = (size_t)blockIdx.x * blockDim.x + threadIdx.x; k < n;
       k += (size_t)gridDim.x * blockDim.x)
    p[k] = s;
}

__global__ void k_transpose(const float* __restrict__ in, float* __restrict__ out) {
  __shared__ float tile[32][33];
  int bx = blockIdx.x, by = blockIdx.y;
  int x = threadIdx.x, y = threadIdx.y;
  #pragma unroll
  for (int j = 0; j < 4; ++j)
    tile[y + j * 8][x] = in[(by * 32 + y + j * 8) * 512 + bx * 32 + x];
  __syncthreads();
  #pragma unroll
  for (int j = 0; j < 4; ++j)
    out[(bx * 32 + y + j * 8) * 1536 + by * 32 + x] = tile[x][y + j * 8];
}

__global__ __launch_bounds__(256) void k_proj(const float* __restrict__ emb0,
                                              const float* __restrict__ emb1,
                                              const float* __restrict__ Wt_ih,
                                              float* __restrict__ proj0,
                                              float* __restrict__ proj1) {
  __shared__ float a[8][NE];
  int g0 = blockIdx.x * 8;
  int tid = threadIdx.x;
  for (int i = tid; i < 8 * NE; i += 256) {
    int v = g0 + (i >> 8);
    int k = i & 255;
    a[i >> 8][k] = (v < NV0) ? emb0[v * NE + k] : emb1[(v - NV0) * NE + k];
  }
  __syncthreads();
  bool is0 = (g0 < NV0);
  int koff = is0 ? 0 : NE;
  float acc[8][6];
  #pragma unroll
  for (int v = 0; v < 8; ++v)
    #pragma unroll
    for (int j = 0; j < 6; ++j) acc[v][j] = 0.f;
  for (int k = 0; k < NE; ++k) {
    const float* wrow = Wt_ih + (size_t)(k + koff) * G3H;
    float w[6];
    #pragma unroll
    for (int j = 0; j < 6; ++j) w[j] = wrow[tid + j * 256];
    #pragma unroll
    for (int v = 0; v < 8; ++v) {
      float av = a[v][k];
      #pragma unroll
      for (int j = 0; j < 6; ++j) acc[v][j] += av * w[j];
    }
  }
  float* outp = is0 ? (proj0 + (size_t)g0 * G3H) : (proj1 + (size_t)(g0 - NV0) * G3H);
  for (int v = 0; v < 8; ++v)
    for (int j = 0; j < 6; ++j)
      outp[(size_t)v * G3H + tid + j * 256] = acc[v][j];
}

// W_hh split: tile tt = (hh>>4)*3 + g  (32 hh16-blocks x 3 gates = 96 tiles of 16x512)
__global__ void k_wsplit(const float* __restrict__ W_hh, u16* __restrict__ Wfh,
                         u16* __restrict__ Wfl) {
  int idx = blockIdx.x * blockDim.x + threadIdx.x;
  if (idx >= G3H * NH) return;
  int row = idx >> 9, k = idx & 511;
  int g = row >> 9, hh = row & 511;
  int tt = (hh >> 4) * 3 + g;
  size_t phys = ((size_t)tt * 64 + (k >> 3)) * 128 + (hh & 15) * 8 + (k & 7);
  float v = W_hh[idx];
  u16 hi = bf16_hi(v);
  Wfh[phys] = hi;
  Wfl[phys] = bf16_hi(v - bf16_f(hi));
}

__global__ void k_wsplit_dec(const float* __restrict__ W, u16* __restrict__ Wh,
                             u16* __restrict__ Wl, int R) {
  int idx = blockIdx.x * blockDim.x + threadIdx.x;
  if (idx >= R * 512) return;
  int row = idx >> 9, k = idx & 511;
  size_t phys = ((size_t)(row >> 4) * 64 + (k >> 3)) * 128 + (row & 15) * 8 + (k & 7);
  float v = W[idx];
  u16 hi = bf16_hi(v);
  Wh[phys] = hi;
  Wl[phys] = bf16_hi(v - bf16_f(hi));
}

// Fused planning (r16-proven): serial pass computes levels + item list + node
// slot positions; parallel pass pre-resolves meta2[pos] = {tb|k0<<17, par|k1<<17}.
__global__ __launch_bounds__(256) void k_plan(const int* __restrict__ cond,
                                              const int* __restrict__ tok0,
                                              const int* __restrict__ tok1,
                                              const float* __restrict__ hidden,
                                              u32* __restrict__ bufp,
                                              int* __restrict__ items,
                                              int* __restrict__ nitems,
                                              int2* __restrict__ meta2) {
  __shared__ int c_lds[NT];
  __shared__ int lvl[NT + 1];
  __shared__ int off[NT + 1];
  __shared__ int pos_lds[NT];
  int b = blockIdx.x, tid = threadIdx.x;
  for (int h = tid; h < NH; h += 256) bufp[b * NH + h] = pack_hl(hidden[b * NH + h]);
  for (int i = tid; i < NT; i += 256) c_lds[i] = cond[b * NT + i];
  for (int i = tid; i <= NT; i += 256) off[i] = 0;
  __syncthreads();
  if (tid == 0) {
    lvl[0] = 0;
    for (int t = 0; t < NT; ++t) {
      int l = lvl[c_lds[t]] + 1;
      lvl[t + 1] = l;
      off[l - 1]++;                       // counts
    }
    int off0 = 0, io = 0;
    for (int p = 0; p <= NT; ++p) {
      int n = off[p];
      off[p] = off0;                      // counts -> offsets
      for (int g0 = 0; g0 < n; g0 += 16) {
        int nb = n - g0; if (nb > 16) nb = 16;
        items[b * 1024 + io++] = ((b * 1024 + off0 + g0) << 6) | nb;
      }
      off0 += n;
    }
    nitems[b] = io;
    for (int t = 0; t < NT; ++t) {        // node -> slot position
      int p = lvl[t + 1] - 1;
      pos_lds[t] = off[p]++;
    }
  }
  __syncthreads();
  for (int t = tid; t < NT; t += 256) {
    int tb = (t + 1) * NB + b;
    int par = c_lds[t] * NB + b;
    int k0 = tok0[b * NT + t];
    int k1 = tok1[b * NT + t];
    int2 v;
    v.x = tb | (k0 << 17);
    v.y = par | (k1 << 17);
    meta2[b * 1024 + pos_lds[t]] = v;
  }
}

// ---------------- recurrence: value-sync + W-IN-REGISTERS ----------------
// Grid = 16 chunks x 32 batches = 512 blocks x 2 waves = 1024 waves on 1024
// SIMDs -> 1 wave/SIMD, so each wave may use ~450 VGPRs at no occupancy cost.
// Each wave PREFETCHES its entire W slab (hb x 3 gates, hi+lo fragment form =
// 96 bf16x8 = 384 VGPRs) ONCE; per-item MFMA then reads only LDS (A) +
// registers (B) -- the ~1.3us/item W L2-stream leaves the critical path.
// Value-sync (r15-proven): spin directly on sentinel-filled parent-state words.

__global__ __launch_bounds__(128, 1) void rnn_steps(
    const int* __restrict__ items, const int* __restrict__ nitems,
    const int2* __restrict__ meta2,
    const u16* __restrict__ Wfh, const u16* __restrict__ Wfl,
    const float* __restrict__ proj0, const float* __restrict__ proj1,
    const float* __restrict__ b_ih, const float* __restrict__ b_hh,
    u32* __restrict__ bufp) {
  __shared__ unsigned char hds_h[16 * 1024];
  __shared__ unsigned char hds_l[16 * 1024];
  int tid = threadIdx.x;
  int w = tid >> 6, lane = tid & 63, q = lane >> 4, m = lane & 15;
  int c = blockIdx.x & (NCHUNK - 1);
  int b = blockIdx.x >> 4;
  int nIt = nitems[b];
  const int* myItems = items + b * 1024;
  // wave-invariant constants
  int hb = c * 2 + w;          // hh16-block owned by this wave
  int hh = hb * 16 + m;
  float bir = b_ih[hh] + b_hh[hh];
  float biz = b_ih[NH + hh] + b_hh[NH + hh];
  float bin = b_ih[2 * NH + hh];
  float bhn = b_hh[2 * NH + hh];
  // ---- prefetch W slab into registers (static indexing, fully unrolled) ----
  bf16x8 wfr[16][2], wfz[16][2], wfn[16][2];
  {
    const u16* wh = Wfh + (size_t)hb * 3 * 8192;
    const u16* wl = Wfl + (size_t)hb * 3 * 8192;
    #pragma unroll
    for (int s = 0; s < 16; ++s) {
      int koff = (s * 4 + q) * 128 + m * 8;
      wfr[s][0] = *(const bf16x8*)(wh + koff);
      wfr[s][1] = *(const bf16x8*)(wl + koff);
      wfz[s][0] = *(const bf16x8*)(wh + 8192 + koff);
      wfz[s][1] = *(const bf16x8*)(wl + 8192 + koff);
      wfn[s][0] = *(const bf16x8*)(wh + 16384 + koff);
      wfn[s][1] = *(const bf16x8*)(wl + 16384 + koff);
    }
  }
  for (int j = 0; j < nIt; ++j) {
    int desc = myItems[j];
    int start = (desc >> 6) & 0x7FFF;
    int nb = desc & 63;
    // ---- direct meta loads for this thread's 4 nodes ----
    int2 md[4];
    #pragma unroll
    for (int i = 0; i < 4; ++i) {
      int node = q * 4 + i;
      md[i] = meta2[start + (node < nb ? node : 0)];
    }
    // ---- gi gather (independent of parents): overlaps everything below ----
    f32x4 aR, aZ, aN;
    float gin[4];
    #pragma unroll
    for (int i = 0; i < 4; ++i) {
      const float* p0 = proj0 + (size_t)(((u32)md[i].x) >> 17) * G3H;
      const float* p1 = proj1 + (size_t)(((u32)md[i].y) >> 17) * G3H;
      aR[i] = p0[hh] + p1[hh] + bir;
      aZ[i] = p0[NH + hh] + p1[NH + hh] + biz;
      gin[i] = p0[2 * NH + hh] + p1[2 * NH + hh] + bin;
      aN[i] = bhn;
    }
    __syncthreads();   // LDS protect: previous item's MFMA reads complete
    // ---- stage nb parent states: SPIN ON DATA (8 u64 in flight x 2 passes) ----
    for (int idx = tid; idx < nb * 16; idx += 128) {
      int r = idx >> 4, seg = idx & 15;
      int par = meta2[start + r].y & 0x1FFFF;
      size_t src = (size_t)par * NH + seg * 32;
      int swz = (r & 7) << 4;
      #pragma unroll
      for (int half = 0; half < 2; ++half) {
        u64 dv[8];
        #pragma unroll
        for (int k2 = 0; k2 < 8; ++k2)
          dv[k2] = __hip_atomic_load((const u64*)&bufp[src + half * 16 + k2 * 2],
                                     __ATOMIC_RELAXED, __HIP_MEMORY_SCOPE_AGENT);
        for (;;) {
          bool ok = true;
          #pragma unroll
          for (int k2 = 0; k2 < 8; ++k2)
            if ((u32)dv[k2] == SENT || (u32)(dv[k2] >> 32) == SENT) ok = false;
          if (ok) break;
          __builtin_amdgcn_s_sleep(1);
          #pragma unroll
          for (int k2 = 0; k2 < 8; ++k2)
            if ((u32)dv[k2] == SENT || (u32)(dv[k2] >> 32) == SENT)
              dv[k2] = __hip_atomic_load((const u64*)&bufp[src + half * 16 + k2 * 2],
                                         __ATOMIC_RELAXED, __HIP_MEMORY_SCOPE_AGENT);
        }
        #pragma unroll
        for (int k2 = 0; k2 < 8; ++k2) {
          u32 e0 = (u32)dv[k2], e1 = (u32)(dv[k2] >> 32);
          int wi = seg * 32 + half * 16 + k2 * 2;
          int a = r * 1024 + (((wi >> 3) * 16) ^ swz) + ((2 * wi) & 15);
          *(u32*)(hds_h + a) = (e0 & 0xFFFFu) | (e1 << 16);
          *(u32*)(hds_l + a) = (e0 >> 16) | (e1 & 0xFFFF0000u);
        }
      }
    }
    __syncthreads();
    // ---- MFMA: B operands from REGISTERS, A from LDS; fully unrolled ----
    #pragma unroll
    for (int s = 0; s < 16; ++s) {
      int ab = m * 1024 + (((s * 64) + (q * 16)) ^ ((m & 7) << 4));
      bf16x8 ah = *(const bf16x8*)(hds_h + ab);
      bf16x8 al = *(const bf16x8*)(hds_l + ab);
      aR = __builtin_amdgcn_mfma_f32_16x16x32_bf16(ah, wfr[s][0], aR, 0, 0, 0);
      aR = __builtin_amdgcn_mfma_f32_16x16x32_bf16(ah, wfr[s][1], aR, 0, 0, 0);
      aR = __builtin_amdgcn_mfma_f32_16x16x32_bf16(al, wfr[s][0], aR, 0, 0, 0);
      aZ = __builtin_amdgcn_mfma_f32_16x16x32_bf16(ah, wfz[s][0], aZ, 0, 0, 0);
      aZ = __builtin_amdgcn_mfma_f32_16x16x32_bf16(ah, wfz[s][1], aZ, 0, 0, 0);
      aZ = __builtin_amdgcn_mfma_f32_16x16x32_bf16(al, wfz[s][0], aZ, 0, 0, 0);
      aN = __builtin_amdgcn_mfma_f32_16x16x32_bf16(ah, wfn[s][0], aN, 0, 0, 0);
      aN = __builtin_amdgcn_mfma_f32_16x16x32_bf16(ah, wfn[s][1], aN, 0, 0, 0);
      aN = __builtin_amdgcn_mfma_f32_16x16x32_bf16(al, wfn[s][0], aN, 0, 0, 0);
    }
    // ---- in-register GRU epilogue; packed u32 agent-atomic state stores ----
    // (no drain/publish: the data IS the flag)
    #pragma unroll
    for (int i = 0; i < 4; ++i) {
      int node = q * 4 + i;
      if (node < nb) {
        float rg = 1.f / (1.f + __expf(-aR[i]));
        float zg = 1.f / (1.f + __expf(-aZ[i]));
        float nn = 1.f - 2.f / (1.f + __expf(2.f * (gin[i] + rg * aN[i])));
        int hofs = node * 1024 + ((hh * 2) ^ ((node & 7) << 4));
        float hp = bf16_f(*(const u16*)(hds_h + hofs)) + bf16_f(*(const u16*)(hds_l + hofs));
        float hn = (1.f - zg) * nn + zg * hp;
        __hip_atomic_store(&bufp[(size_t)(md[i].x & 0x1FFFF) * NH + hh], pack_hl(hn),
                           __ATOMIC_RELAXED, __HIP_MEMORY_SCOPE_AGENT);
      }
    }
  }
}

// ---------------- decode GEMM: MFMA bf16 3-split, 64x128 tiles ----------------

__global__ __launch_bounds__(256) void k_dec(const u32* __restrict__ bufp,
                                             const u16* __restrict__ Wh,
                                             const u16* __restrict__ Wl,
                                             const float* __restrict__ bias,
                                             float* __restrict__ out, int N) {
  __shared__ u16 Ah[64 * 128];
  __shared__ u16 Al[64 * 128];
  int tid = threadIdx.x;
  int w = tid >> 6, lane = tid & 63, q = lane >> 4, m = lane & 15;
  int n0 = blockIdx.x * 128, m0 = blockIdx.y * 64;
  f32x4 acc[8];
  #pragma unroll
  for (int n = 0; n < 8; ++n) acc[n] = (f32x4){0.f, 0.f, 0.f, 0.f};
  for (int c = 0; c < 4; ++c) {
    __syncthreads();
    #pragma unroll
    for (int r = 0; r < 8; ++r) {
      int idx = r * 256 + tid;           // 2048 16B-loads = 64 rows x 32 segs
      int row = idx >> 5, seg = idx & 31;
      int gm = m0 + row;
      size_t bufrow = (size_t)((gm & (NT - 1)) + 1) * NB + (gm >> 10);
      uint4 vv = *(const uint4*)(bufp + bufrow * NH + c * 128 + seg * 4);
      int a = row * 256 + (((seg >> 1) * 16) ^ ((row & 7) << 4)) + (seg & 1) * 8;
      uint2 hp, lp;
      hp.x = (vv.x & 0xFFFFu) | (vv.y << 16);
      hp.y = (vv.z & 0xFFFFu) | (vv.w << 16);
      lp.x = (vv.x >> 16) | (vv.y & 0xFFFF0000u);
      lp.y = (vv.z >> 16) | (vv.w & 0xFFFF0000u);
      *(uint2*)((unsigned char*)Ah + a) = hp;
      *(uint2*)((unsigned char*)Al + a) = lp;
    }
    __syncthreads();
    #pragma unroll
    for (int s = 0; s < 4; ++s) {
      int arow = w * 16 + m;
      int aoff = arow * 256 + (((s * 64) + (q * 16)) ^ ((arow & 7) << 4));
      bf16x8 ah = *(const bf16x8*)((unsigned char*)Ah + aoff);
      bf16x8 al = *(const bf16x8*)((unsigned char*)Al + aoff);
      #pragma unroll
      for (int n = 0; n < 8; ++n) {
        size_t bo = ((size_t)(n0 / 16 + n) * 64 + (c * 16 + s * 4 + q)) * 128 + m * 8;
        bf16x8 bh = *(const bf16x8*)(Wh + bo);
        bf16x8 bl = *(const bf16x8*)(Wl + bo);
        acc[n] = __builtin_amdgcn_mfma_f32_16x16x32_bf16(ah, bh, acc[n], 0, 0, 0);
        acc[n] = __builtin_amdgcn_mfma_f32_16x16x32_bf16(ah, bl, acc[n], 0, 0, 0);
        acc[n] = __builtin_amdgcn_mfma_f32_16x16x32_bf16(al, bh, acc[n], 0, 0, 0);
      }
    }
  }
  #pragma unroll
  for (int n = 0; n < 8; ++n) {
    int col = n0 + n * 16 + m;
    float bv = bias[col];
    #pragma unroll
    for (int i = 0; i < 4; ++i) {
      int mrow = m0 + w * 16 + q * 4 + i;
      out[(size_t)mrow * N + col] = acc[n][i] + bv;
    }
  }
}

__global__ void k_tail(const u32* __restrict__ bufp, float* __restrict__ out) {
  int i = blockIdx.x * blockDim.x + threadIdx.x;
  if (i < NB * NH) out[i] = unpack_hl(bufp[(size_t)NT * NB * NH + i]);
}

// ---------------- launch ----------------

extern "C" void kernel_launch(void* const* d_in, const int* in_sizes, int n_in,
                              void* d_out, int out_size, void* d_ws, size_t ws_size,
                              hipStream_t stream) {
  const int*   tokens0    = (const int*)d_in[0];
  const int*   tokens1    = (const int*)d_in[1];
  const int*   conditions = (const int*)d_in[2];
  const float* hidden     = (const float*)d_in[3];
  const float* emb0       = (const float*)d_in[4];
  const float* emb1       = (const float*)d_in[5];
  const float* W_ih       = (const float*)d_in[6];
  const float* W_hh       = (const float*)d_in[7];
  const float* b_ih       = (const float*)d_in[8];
  const float* b_hh       = (const float*)d_in[9];
  const float* dec0_W     = (const float*)d_in[10];
  const float* dec0_b     = (const float*)d_in[11];
  const float* dec1_W     = (const float*)d_in[12];
  const float* dec1_b     = (const float*)d_in[13];

  char* wsb = (char*)d_ws;
  float* proj0 = (float*)wsb;                      // 12,582,912 B
  float* proj1 = (float*)(wsb + 12582912);         //  3,145,728 B
  float* Wt_ih = (float*)(wsb + 15728640);         //  3,145,728 B (reused below)
  // items/nitems/meta2 overlay Wt_ih's region: used only AFTER k_proj
  int*   items   = (int*)(wsb + 15728640);         // 32*1024 ints = 131,072 B
  int*   nitems  = (int*)(wsb + 15859712);         // 32 ints (pad to 256B)
  int2*  meta2   = (int2*)(wsb + 15859968);        // 32*1024 int2 = 262,144 B
  u32*   bufp  = (u32*)(wsb + 18874368);           // 1025*32*512 u32 = 67,174,400 B
  u16*   Wfh   = (u16*)(wsb + 86048768);           //  1,572,864 B
  u16*   Wfl   = (u16*)(wsb + 87621632);           //  1,572,864 B
  u16*   d0Wh  = (u16*)(wsb + 89194496);           //  2,097,152 B
  u16*   d0Wl  = (u16*)(wsb + 91291648);           //  2,097,152 B
  u16*   d1Wh  = (u16*)(wsb + 93388800);           //    524,288 B
  u16*   d1Wl  = (u16*)(wsb + 93913088);           //    524,288 B

  float* out0 = (float*)d_out;
  float* out1 = out0 + (size_t)NB * NT * NV0;
  float* outT = out1 + (size_t)NB * NT * NV1;

  // Wt_ih produced+consumed first; then its region is reused for dataflow state.
  k_transpose<<<dim3(16, 48), dim3(32, 8), 0, stream>>>(W_ih, Wt_ih);
  k_proj<<<320, 256, 0, stream>>>(emb0, emb1, Wt_ih, proj0, proj1);
  k_sent<<<2048, 256, 0, stream>>>(bufp);
  k_wsplit<<<3072, 256, 0, stream>>>(W_hh, Wfh, Wfl);
  k_wsplit_dec<<<4096, 256, 0, stream>>>(dec0_W, d0Wh, d0Wl, NV0);
  k_wsplit_dec<<<1024, 256, 0, stream>>>(dec1_W, d1Wh, d1Wl, NV1);
  k_plan<<<NB, 256, 0, stream>>>(conditions, tokens0, tokens1, hidden, bufp,
                                 items, nitems, meta2);

  rnn_steps<<<NCHUNK * NB, 128, 0, stream>>>(items, nitems, meta2, Wfh, Wfl,
                                             proj0, proj1, b_ih, b_hh, bufp);

  k_dec<<<dim3(NV0 / 128, (NB * NT) / 64), 256, 0, stream>>>(bufp, d0Wh, d0Wl, dec0_b, out0, NV0);
  k_dec<<<dim3(NV1 / 128, (NB * NT) / 64), 256, 0, stream>>>(bufp, d1Wh, d1Wl, dec1_b, out1, NV1);
  k_tail<<<64, 256, 0, stream>>>(bufp, outT);
}